// Round 6
// baseline (2166.494 us; speedup 1.0000x reference)
//
#include <hip/hip_runtime.h>

// Swin block: LN1 -> shift+window -> qkv GEMM -> MFMA windowed attn -> proj GEMM (linear)
//          -> fused scatter+residual+LN2 -> fc1 GEMM(+GELU) -> fc2 GEMM(+residual)
// B=64, H=W=56, C=384, WS=7, SS=3, NH=12, hd=32, N=49, nW=64, B_=4096, M=200704
// R6: GEMM rewritten as 256x128-tile, 8-wave, double-buffered pipeline with counted
//     vmcnt (s_waitcnt vmcnt(6)) + raw s_barrier + setprio around MFMA clusters.
//     Loads for tile t+1 stay in flight across tile t's compute (T3+T4 minimal, T5).
//     Fragment layout / slot-XOR swizzle / epilogues unchanged (verified, 0 conflicts).

typedef __bf16 bf16x8 __attribute__((ext_vector_type(8)));
typedef float  f32x4  __attribute__((ext_vector_type(4)));
typedef unsigned short u16x8 __attribute__((ext_vector_type(8)));
typedef unsigned short u16x4 __attribute__((ext_vector_type(4)));

__device__ __forceinline__ unsigned short f2bf(float f) {
    unsigned int u = __builtin_bit_cast(unsigned int, f);
    u += 0x7fffu + ((u >> 16) & 1u);   // RNE
    return (unsigned short)(u >> 16);
}
__device__ __forceinline__ float bf2f(unsigned short h) {
    return __builtin_bit_cast(float, (unsigned int)h << 16);
}

// ---------------- weight transpose + cast: W[K,N] f32 -> Bt[N,K] bf16 ----------------
__global__ __launch_bounds__(256) void k_transpose(const float* __restrict__ W,
                                                   unsigned short* __restrict__ Bt,
                                                   int K, int N) {
    int idx = blockIdx.x * 256 + threadIdx.x;
    if (idx >= N * K) return;
    int n = idx / K, k = idx - n * K;
    Bt[idx] = f2bf(W[(long)k * N + n]);
}

// ---------------- bias+mask table: tbl[mt][h][i][j], 4*12*64*64 f32 ----------------
__global__ __launch_bounds__(256) void k_btab(const float* __restrict__ rpb,
                                              float* __restrict__ tbl) {
    int idx = blockIdx.x * 256 + threadIdx.x;
    if (idx >= 4 * 12 * 4096) return;
    int j = idx & 63, i = (idx >> 6) & 63;
    int slab = idx >> 12;            // mt*12 + h
    int h = slab % 12, mt = slab / 12;
    float v;
    if (j >= 49)      v = -30000.f;
    else if (i >= 49) v = 0.f;
    else {
        int ith = i / 7, itw = i - ith * 7;
        int jth = j / 7, jtw = j - jth * 7;
        v = rpb[((ith - jth + 6) * 13 + (itw - jtw + 6)) * 12 + h];
        bool m = ((mt & 1) && ((ith < 4) != (jth < 4))) ||
                 ((mt & 2) && ((itw < 4) != (jtw < 4)));
        if (m) v -= 100.f;
    }
    tbl[idx] = v;
}

// ---------------- LN1 + cyclic shift(-3,-3) + window partition ----------------
__global__ __launch_bounds__(256) void k_ln1(const float* __restrict__ x,
                                             const float* __restrict__ g,
                                             const float* __restrict__ bb,
                                             unsigned short* __restrict__ xw) {
    int wid = threadIdx.x >> 6, lane = threadIdx.x & 63;
    int tok = blockIdx.x * 4 + wid;                 // < 200704
    int t  = tok % 49; int b_ = tok / 49;
    int wi = b_ & 63;  int b  = b_ >> 6;
    int th = t / 7, tw = t - th * 7;
    int hs = (wi >> 3) * 7 + th + 3; if (hs >= 56) hs -= 56;
    int vs = (wi & 7) * 7 + tw + 3;  if (vs >= 56) vs -= 56;
    const float2* row = (const float2*)(x + ((long)b * 3136 + hs * 56 + vs) * 384);
    float2 v[3]; float s = 0.f;
    #pragma unroll
    for (int i = 0; i < 3; ++i) { v[i] = row[lane + 64 * i]; s += v[i].x + v[i].y; }
    #pragma unroll
    for (int o = 32; o; o >>= 1) s += __shfl_xor(s, o);
    float mean = s * (1.f / 384.f);
    float q = 0.f;
    #pragma unroll
    for (int i = 0; i < 3; ++i) {
        float dx = v[i].x - mean, dy = v[i].y - mean; q += dx * dx + dy * dy;
    }
    #pragma unroll
    for (int o = 32; o; o >>= 1) q += __shfl_xor(q, o);
    float inv = rsqrtf(q * (1.f / 384.f) + 1e-5f);
    unsigned short* orow = xw + (long)tok * 384;
    #pragma unroll
    for (int i = 0; i < 3; ++i) {
        int c = i * 128 + lane * 2;
        unsigned int p = (unsigned int)f2bf((v[i].x - mean) * inv * g[c] + bb[c])
                       | ((unsigned int)f2bf((v[i].y - mean) * inv * g[c + 1] + bb[c + 1]) << 16);
        *(unsigned int*)(orow + c) = p;
    }
}

// ------- fused un-roll scatter + residual + LN2: out = x + gather(projout); h2 = LN2(out) -------
__global__ __launch_bounds__(256) void k_scln(const unsigned short* __restrict__ po,
                                              const float* __restrict__ x,
                                              const float* __restrict__ g,
                                              const float* __restrict__ bb,
                                              float* __restrict__ out,
                                              unsigned short* __restrict__ h2) {
    int wid = threadIdx.x >> 6, lane = threadIdx.x & 63;
    int tok = blockIdx.x * 4 + wid;                 // < 200704
    int b = tok / 3136, rem = tok - b * 3136;
    int hh = rem / 56, ww = rem - hh * 56;
    int u = (hh >= 3) ? hh - 3 : hh + 53;           // inverse roll(+3)
    int v = (ww >= 3) ? ww - 3 : ww + 53;
    int wr = u / 7, th = u - wr * 7;
    int wc = v / 7, tw = v - wc * 7;
    long src = ((long)((b << 6) + wr * 8 + wc) * 49 + th * 7 + tw) * 384;
    const unsigned int* prow = (const unsigned int*)(po + src);    // 2 bf16 / uint
    const float2* xrow = (const float2*)(x + (long)tok * 384);
    float2 o[3]; float s = 0.f;
    #pragma unroll
    for (int i = 0; i < 3; ++i) {
        unsigned int pb = prow[lane + 64 * i];
        float2 xv = xrow[lane + 64 * i];
        o[i].x = xv.x + bf2f((unsigned short)(pb & 0xffffu));
        o[i].y = xv.y + bf2f((unsigned short)(pb >> 16));
        s += o[i].x + o[i].y;
    }
    float2* orow = (float2*)(out + (long)tok * 384);
    #pragma unroll
    for (int i = 0; i < 3; ++i) orow[lane + 64 * i] = o[i];
    #pragma unroll
    for (int of = 32; of; of >>= 1) s += __shfl_xor(s, of);
    float mean = s * (1.f / 384.f);
    float q = 0.f;
    #pragma unroll
    for (int i = 0; i < 3; ++i) {
        float dx = o[i].x - mean, dy = o[i].y - mean; q += dx * dx + dy * dy;
    }
    #pragma unroll
    for (int of = 32; of; of >>= 1) q += __shfl_xor(q, of);
    float inv = rsqrtf(q * (1.f / 384.f) + 1e-5f);
    unsigned short* hrow = h2 + (long)tok * 384;
    #pragma unroll
    for (int i = 0; i < 3; ++i) {
        int c = i * 128 + lane * 2;
        unsigned int p = (unsigned int)f2bf((o[i].x - mean) * inv * g[c] + bb[c])
                       | ((unsigned int)f2bf((o[i].y - mean) * inv * g[c + 1] + bb[c + 1]) << 16);
        *(unsigned int*)(hrow + c) = p;
    }
}

// ---------------- MFMA windowed attention: 1 wave = 1 (window, head), 4 waves/block ----------------
__global__ __launch_bounds__(256) void k_attn(const unsigned short* __restrict__ qkv,
                                              const float* __restrict__ tbl,     // [4][12][64][64]
                                              unsigned short* __restrict__ aout, // [nwin*49,384]
                                              int win_base) {
    __shared__ unsigned short Plds[4][64][72];
    __shared__ unsigned short Vlds[4][32][72];
    int tid = threadIdx.x;
    int w = tid >> 6, lane = tid & 63;
    int wg = blockIdx.x * 4 + w;
    int lw = wg / 12;                  // local window
    int h  = wg - lw * 12;             // head
    int g  = lane >> 4, c = lane & 15;
    const unsigned short* base = qkv + (long)lw * 49 * 1152;

    int wi = (win_base + lw) & 63;
    int mt = ((wi >> 3) == 7 ? 1 : 0) | ((wi & 7) == 7 ? 2 : 0);
    const float* tb = tbl + ((long)(mt * 12 + h) << 12);

    // ---- stage V (permuted rows) into LDS; zero-fill padding rows 49..63 ----
    #pragma unroll
    for (int it = 0; it < 4; ++it) {
        int t = it * 64 + lane;        // t < 256
        int j = t >> 2, o = t & 3;
        int pj = 4 * (j & 15) + (j >> 4);     // phys slot
        if (j < 49) {
            u16x8 vv = *(const u16x8*)(base + (long)j * 1152 + 768 + h * 32 + o * 8);
            #pragma unroll
            for (int e = 0; e < 8; ++e) Vlds[w][o * 8 + e][pj] = vv[e];
        } else {
            #pragma unroll
            for (int e = 0; e < 8; ++e) Vlds[w][o * 8 + e][pj] = 0;
        }
    }

    // ---- Q and K fragments straight from global ----
    bf16x8 qa[4], kb[4];
    #pragma unroll
    for (int m = 0; m < 4; ++m) {
        int qr = 16 * m + c; if (qr > 48) qr = 48;
        qa[m] = *(const bf16x8*)(base + (long)qr * 1152 + h * 32 + 8 * g);
    }
    #pragma unroll
    for (int n = 0; n < 4; ++n) {
        int jr = 16 * n + c; if (jr > 48) jr = 48;
        kb[n] = *(const bf16x8*)(base + (long)jr * 1152 + 384 + h * 32 + 8 * g);
    }

    // ---- S = Q.K^T : 16 MFMA, single k-step ----
    f32x4 s[4][4];
    #pragma unroll
    for (int m = 0; m < 4; ++m)
        #pragma unroll
        for (int n = 0; n < 4; ++n) {
            s[m][n] = (f32x4){0.f, 0.f, 0.f, 0.f};
            s[m][n] = __builtin_amdgcn_mfma_f32_16x16x32_bf16(qa[m], kb[n], s[m][n], 0, 0, 0);
        }

    // ---- scale + bias/mask table; softmax rows in C/D layout ----
    #pragma unroll
    for (int m = 0; m < 4; ++m)
        #pragma unroll
        for (int n = 0; n < 4; ++n) {
            #pragma unroll
            for (int ii = 0; ii < 4; ++ii) {
                int i = 16 * m + 4 * g + ii, j = 16 * n + c;
                s[m][n][ii] = s[m][n][ii] * 0.17677669529663687f + tb[i * 64 + j];
            }
        }
    float inv[4][4];
    #pragma unroll
    for (int m = 0; m < 4; ++m) {
        #pragma unroll
        for (int ii = 0; ii < 4; ++ii) {
            float mx = fmaxf(fmaxf(s[m][0][ii], s[m][1][ii]), fmaxf(s[m][2][ii], s[m][3][ii]));
            #pragma unroll
            for (int o = 1; o < 16; o <<= 1) mx = fmaxf(mx, __shfl_xor(mx, o));
            float sm = 0.f;
            #pragma unroll
            for (int n = 0; n < 4; ++n) {
                float p = __expf(s[m][n][ii] - mx);
                s[m][n][ii] = p; sm += p;
            }
            #pragma unroll
            for (int o = 1; o < 16; o <<= 1) sm += __shfl_xor(sm, o);
            inv[m][ii] = 1.f / sm;
        }
    }

    // ---- P -> LDS: packed b64 writes at permuted cols phys(16n+c)=4c+n ----
    #pragma unroll
    for (int m = 0; m < 4; ++m)
        #pragma unroll
        for (int ii = 0; ii < 4; ++ii) {
            int r = 16 * m + 4 * g + ii;
            u16x4 pk;
            #pragma unroll
            for (int n = 0; n < 4; ++n) pk[n] = f2bf(s[m][n][ii]);
            *(u16x4*)&Plds[w][r][4 * c] = pk;
        }

    __syncthreads();

    // ---- O = P.V : 2 k-steps over 64 phys slots ----
    f32x4 o2[4][2];
    #pragma unroll
    for (int m = 0; m < 4; ++m)
        #pragma unroll
        for (int n = 0; n < 2; ++n) o2[m][n] = (f32x4){0.f, 0.f, 0.f, 0.f};
    #pragma unroll
    for (int ks = 0; ks < 2; ++ks) {
        bf16x8 pa[4], vb[2];
        #pragma unroll
        for (int m = 0; m < 4; ++m)
            pa[m] = *(const bf16x8*)&Plds[w][c + 16 * m][32 * ks + 8 * g];
        #pragma unroll
        for (int n = 0; n < 2; ++n)
            vb[n] = *(const bf16x8*)&Vlds[w][c + 16 * n][32 * ks + 8 * g];
        #pragma unroll
        for (int m = 0; m < 4; ++m)
            #pragma unroll
            for (int n = 0; n < 2; ++n)
                o2[m][n] = __builtin_amdgcn_mfma_f32_16x16x32_bf16(pa[m], vb[n], o2[m][n], 0, 0, 0);
    }

    // ---- store O rows < 49, scaled by 1/rowsum ----
    #pragma unroll
    for (int m = 0; m < 4; ++m)
        #pragma unroll
        for (int ii = 0; ii < 4; ++ii) {
            int i = 16 * m + 4 * g + ii;
            if (i < 49) {
                unsigned short* orow = aout + ((long)lw * 49 + i) * 384 + h * 32;
                #pragma unroll
                for (int n = 0; n < 2; ++n)
                    orow[c + 16 * n] = f2bf(o2[m][n][ii] * inv[m][ii]);
            }
        }
}

// ---------------- bf16 MFMA GEMM, 256x128 tile, BK=64, 8 waves, dbuf+counted-vmcnt ----------------
// A[M,K] bf16 rm, Bt[N,K] bf16 rm. LDS slot-XOR swizzle (source pre-swizzle, m173).
// Pipeline per K-tile t: issue 6 global_load_lds for t+1 -> s_waitcnt vmcnt(6) (t's loads
// landed, t+1's in flight) -> s_barrier -> ds_read+MFMA (2 k-steps, setprio around MFMA)
// -> s_barrier (protects buffer restaged at t+2). Last tile: vmcnt(0).
// EPI: 0 = bf16 out, 1 = bf16 out + exact GELU, 3 = f32 out + res (rows m_base+row)
template<int EPI>
__global__ __launch_bounds__(512) void k_gemm(
    const unsigned short* __restrict__ A,
    const unsigned short* __restrict__ Bt,
    const float* __restrict__ bias,
    unsigned short* outb, float* outf, const float* res,
    int M, int N, int K, int m_base)
{
    __shared__ unsigned short As[2][256][64];   // 64 KB
    __shared__ unsigned short Bs[2][128][64];   // 32 KB
    int nwg = gridDim.x * gridDim.y;
    int bid = blockIdx.y * gridDim.x + blockIdx.x;
    int qq = nwg >> 3, rr = nwg & 7;
    int xcd = bid & 7, idx = bid >> 3;
    int swz = (xcd < rr) ? (xcd * (qq + 1) + idx) : (rr * (qq + 1) + (xcd - rr) * qq + idx);
    int m0 = (swz / gridDim.x) << 8;
    int n0 = (swz % gridDim.x) << 7;

    int tid = threadIdx.x, wid = tid >> 6, lane = tid & 63;
    int wr = wid >> 1, wc = wid & 1;            // 4M x 2N waves, 64x64 out each
    f32x4 acc[4][4];
    #pragma unroll
    for (int i = 0; i < 4; ++i)
        #pragma unroll
        for (int j = 0; j < 4; ++j)
            acc[i][j] = (f32x4){0.f, 0.f, 0.f, 0.f};

    // staging addresses: wave stages 32 A-rows + 16 B-rows per K-tile.
    // LDS slot s of row r holds global k-slot s^(r&7) (gload_lds dest is linear).
    int lrow = lane >> 3;
    int lcol = (lane & 7) ^ lrow;
    const unsigned short* Ag = A  + (long)(m0 + wid * 32 + lrow) * K + lcol * 8;
    const unsigned short* Bg = Bt + (long)(n0 + wid * 16 + lrow) * K + lcol * 8;

    int nt = K >> 6;
    auto stage = [&](int buf, int t) {
        int k0 = t << 6;
        #pragma unroll
        for (int c = 0; c < 4; ++c)
            __builtin_amdgcn_global_load_lds(
                (const __attribute__((address_space(1))) void*)(Ag + k0 + c * 8 * K),
                (__attribute__((address_space(3))) void*)(&As[buf][wid * 32 + c * 8][0]), 16, 0, 0);
        #pragma unroll
        for (int c = 0; c < 2; ++c)
            __builtin_amdgcn_global_load_lds(
                (const __attribute__((address_space(1))) void*)(Bg + k0 + c * 8 * K),
                (__attribute__((address_space(3))) void*)(&Bs[buf][wid * 16 + c * 8][0]), 16, 0, 0);
    };

    stage(0, 0);
    int cur = 0;
    for (int t = 0; t < nt; ++t) {
        if (t + 1 < nt) {
            stage(cur ^ 1, t + 1);
            asm volatile("s_waitcnt vmcnt(6)" ::: "memory");   // t's 6 landed; t+1's fly on
        } else {
            asm volatile("s_waitcnt vmcnt(0)" ::: "memory");
        }
        __builtin_amdgcn_s_barrier();
        #pragma unroll
        for (int kk = 0; kk < 2; ++kk) {
            bf16x8 af[4], bfr[4];
            #pragma unroll
            for (int mi = 0; mi < 4; ++mi) {
                int r = wr * 64 + mi * 16 + (lane & 15);
                int slot = (kk * 4 + (lane >> 4)) ^ (r & 7);
                af[mi] = *reinterpret_cast<const bf16x8*>(&As[cur][r][slot * 8]);
            }
            #pragma unroll
            for (int ni = 0; ni < 4; ++ni) {
                int r = wc * 64 + ni * 16 + (lane & 15);
                int slot = (kk * 4 + (lane >> 4)) ^ (r & 7);
                bfr[ni] = *reinterpret_cast<const bf16x8*>(&Bs[cur][r][slot * 8]);
            }
            __builtin_amdgcn_s_setprio(1);
            #pragma unroll
            for (int mi = 0; mi < 4; ++mi)
                #pragma unroll
                for (int ni = 0; ni < 4; ++ni)
                    acc[mi][ni] = __builtin_amdgcn_mfma_f32_16x16x32_bf16(
                        af[mi], bfr[ni], acc[mi][ni], 0, 0, 0);
            __builtin_amdgcn_s_setprio(0);
        }
        asm volatile("" ::: "memory");
        __builtin_amdgcn_s_barrier();     // all reads of buf[cur] done before t+2 restages it
        cur ^= 1;
    }

    #pragma unroll
    for (int mi = 0; mi < 4; ++mi) {
        #pragma unroll
        for (int ni = 0; ni < 4; ++ni) {
            int col = n0 + wc * 64 + ni * 16 + (lane & 15);
            float bv = bias[col];
            #pragma unroll
            for (int i = 0; i < 4; ++i) {
                int row = m0 + wr * 64 + mi * 16 + (lane >> 4) * 4 + i;
                float v = acc[mi][ni][i] + bv;
                if constexpr (EPI == 0) {
                    outb[(long)row * N + col] = f2bf(v);
                } else if constexpr (EPI == 1) {
                    outb[(long)row * N + col] = f2bf(0.5f * v * (1.f + erff(v * 0.70710678f)));
                } else {
                    long oidx = (long)(m_base + row) * 384 + col;
                    outf[oidx] = v + res[oidx];
                }
            }
        }
    }
}

extern "C" void kernel_launch(void* const* d_in, const int* in_sizes, int n_in,
                              void* d_out, int out_size, void* d_ws, size_t ws_size,
                              hipStream_t stream) {
    (void)in_sizes; (void)n_in; (void)out_size;
    const float* x     = (const float*)d_in[0];
    const float* n1g   = (const float*)d_in[1];
    const float* n1b   = (const float*)d_in[2];
    const float* qkvw  = (const float*)d_in[3];
    const float* qkvb  = (const float*)d_in[4];
    const float* rpb   = (const float*)d_in[5];
    const float* projw = (const float*)d_in[6];
    const float* projb = (const float*)d_in[7];
    const float* n2g   = (const float*)d_in[8];
    const float* n2b   = (const float*)d_in[9];
    const float* fc1w  = (const float*)d_in[10];
    const float* fc1b  = (const float*)d_in[11];
    const float* fc2w  = (const float*)d_in[12];
    const float* fc2b  = (const float*)d_in[13];
    float* out = (float*)d_out;

    const long Mtot = 200704;
    auto pad = [](size_t b) { return (b + 255) & ~(size_t)255; };
    size_t fixed = pad((size_t)1152 * 384 * 2) + pad((size_t)384 * 384 * 2)
                 + pad((size_t)1536 * 384 * 2) + pad((size_t)384 * 1536 * 2)
                 + pad((size_t)4 * 12 * 4096 * 4)
                 + pad((size_t)Mtot * 384 * 2)      // xw / h2
                 + pad((size_t)Mtot * 384 * 2);     // projout (full, chunk-independent)
    int nc = 1;
    while (nc < 8) {
        size_t rows = Mtot / nc;
        if (fixed + pad(rows * 1536 * 2) + pad(rows * 384 * 2) <= ws_size) break;
        nc <<= 1;
    }
    long rows = Mtot / nc;            // rows per chunk, multiple of 256 and 49
    int  mb   = (int)(rows >> 8);     // 256-row tiles per chunk
    int  wpc  = (int)(rows / 49);     // windows per chunk (multiple of 64)

    char* ws = (char*)d_ws;
    size_t off = 0;
    auto alloc = [&](size_t bytes) { char* p = ws + off; off += (bytes + 255) & ~(size_t)255; return p; };
    unsigned short* BtQ  = (unsigned short*)alloc((size_t)1152 * 384 * 2);
    unsigned short* BtP  = (unsigned short*)alloc((size_t)384 * 384 * 2);
    unsigned short* Bt1  = (unsigned short*)alloc((size_t)1536 * 384 * 2);
    unsigned short* Bt2  = (unsigned short*)alloc((size_t)384 * 1536 * 2);
    float*          tbl  = (float*)alloc((size_t)4 * 12 * 4096 * 4);
    unsigned short* xw   = (unsigned short*)alloc((size_t)Mtot * 384 * 2);   // xw, reused as h2
    unsigned short* pout = (unsigned short*)alloc((size_t)Mtot * 384 * 2);   // proj out (window order)
    unsigned short* bufB = (unsigned short*)alloc((size_t)rows * 1536 * 2);  // qkv / fc1 chunk
    unsigned short* attb = (unsigned short*)alloc((size_t)rows * 384 * 2);   // attn-out chunk

    k_transpose<<<dim3((1152 * 384 + 255) / 256), 256, 0, stream>>>(qkvw, BtQ, 384, 1152);
    k_transpose<<<dim3((384 * 384 + 255) / 256), 256, 0, stream>>>(projw, BtP, 384, 384);
    k_transpose<<<dim3((1536 * 384 + 255) / 256), 256, 0, stream>>>(fc1w, Bt1, 384, 1536);
    k_transpose<<<dim3((384 * 1536 + 255) / 256), 256, 0, stream>>>(fc2w, Bt2, 1536, 384);
    k_btab<<<dim3(768), 256, 0, stream>>>(rpb, tbl);

    k_ln1<<<dim3(50176), 256, 0, stream>>>(x, n1g, n1b, xw);

    // attention phase
    for (int c = 0; c < nc; ++c) {
        const unsigned short* Ax = xw + (size_t)c * rows * 384;
        k_gemm<0><<<dim3(9, mb), 512, 0, stream>>>(Ax, BtQ, qkvb, bufB, nullptr, nullptr,
                                                   (int)rows, 1152, 384, 0);
        k_attn<<<dim3(wpc * 3), 256, 0, stream>>>(bufB, tbl, attb, c * wpc);
        k_gemm<0><<<dim3(3, mb), 512, 0, stream>>>(attb, BtP, projb,
                                                   pout + (size_t)c * rows * 384,
                                                   nullptr, nullptr,
                                                   (int)rows, 384, 384, 0);
    }

    // fused un-roll scatter + residual + LN2 (writes out f32 and xw=h2 bf16)
    k_scln<<<dim3(50176), 256, 0, stream>>>(pout, x, n2g, n2b, out, xw);

    // MLP phase
    for (int c = 0; c < nc; ++c) {
        const unsigned short* Ah = xw + (size_t)c * rows * 384;
        k_gemm<1><<<dim3(12, mb), 512, 0, stream>>>(Ah, Bt1, fc1b, bufB, nullptr, nullptr,
                                                    (int)rows, 1536, 384, 0);
        k_gemm<3><<<dim3(3, mb), 512, 0, stream>>>(bufB, Bt2, fc2b, nullptr, out, out,
                                                   (int)rows, 384, 1536, (int)(c * rows));
    }
}

// Round 7
// 2080.533 us; speedup vs baseline: 1.0413x; 1.0413x over previous
//
#include <hip/hip_runtime.h>

// Swin block: LN1 -> shift+window -> qkv GEMM -> MFMA windowed attn -> proj GEMM (linear)
//          -> fused scatter+residual+LN2 -> fc1 GEMM(+GELU) -> fc2 GEMM(+residual)
// B=64, H=W=56, C=384, WS=7, SS=3, NH=12, hd=32, N=49, nW=64, B_=4096, M=200704
// R7: GEMM = guide's minimum 2-phase schedule on 128x128/4-wave geometry:
//     STAGE(t+1) first -> ds_read+MFMA(t) -> ONE vmcnt(0) AFTER MFMA -> ONE s_barrier.
//     64 KB LDS (2 blocks/CU for TLP), hoisted slot-XOR LDS offsets.
//     (R6 post-mortem: vmcnt-before-compute + 2 barriers + 96KB LDS = 1 block/CU killed TLP.)

typedef __bf16 bf16x8 __attribute__((ext_vector_type(8)));
typedef float  f32x4  __attribute__((ext_vector_type(4)));
typedef unsigned short u16x8 __attribute__((ext_vector_type(8)));
typedef unsigned short u16x4 __attribute__((ext_vector_type(4)));

__device__ __forceinline__ unsigned short f2bf(float f) {
    unsigned int u = __builtin_bit_cast(unsigned int, f);
    u += 0x7fffu + ((u >> 16) & 1u);   // RNE
    return (unsigned short)(u >> 16);
}
__device__ __forceinline__ float bf2f(unsigned short h) {
    return __builtin_bit_cast(float, (unsigned int)h << 16);
}

// ---------------- weight transpose + cast: W[K,N] f32 -> Bt[N,K] bf16 ----------------
__global__ __launch_bounds__(256) void k_transpose(const float* __restrict__ W,
                                                   unsigned short* __restrict__ Bt,
                                                   int K, int N) {
    int idx = blockIdx.x * 256 + threadIdx.x;
    if (idx >= N * K) return;
    int n = idx / K, k = idx - n * K;
    Bt[idx] = f2bf(W[(long)k * N + n]);
}

// ---------------- bias+mask table: tbl[mt][h][i][j], 4*12*64*64 f32 ----------------
__global__ __launch_bounds__(256) void k_btab(const float* __restrict__ rpb,
                                              float* __restrict__ tbl) {
    int idx = blockIdx.x * 256 + threadIdx.x;
    if (idx >= 4 * 12 * 4096) return;
    int j = idx & 63, i = (idx >> 6) & 63;
    int slab = idx >> 12;            // mt*12 + h
    int h = slab % 12, mt = slab / 12;
    float v;
    if (j >= 49)      v = -30000.f;
    else if (i >= 49) v = 0.f;
    else {
        int ith = i / 7, itw = i - ith * 7;
        int jth = j / 7, jtw = j - jth * 7;
        v = rpb[((ith - jth + 6) * 13 + (itw - jtw + 6)) * 12 + h];
        bool m = ((mt & 1) && ((ith < 4) != (jth < 4))) ||
                 ((mt & 2) && ((itw < 4) != (jtw < 4)));
        if (m) v -= 100.f;
    }
    tbl[idx] = v;
}

// ---------------- LN1 + cyclic shift(-3,-3) + window partition ----------------
__global__ __launch_bounds__(256) void k_ln1(const float* __restrict__ x,
                                             const float* __restrict__ g,
                                             const float* __restrict__ bb,
                                             unsigned short* __restrict__ xw) {
    int wid = threadIdx.x >> 6, lane = threadIdx.x & 63;
    int tok = blockIdx.x * 4 + wid;                 // < 200704
    int t  = tok % 49; int b_ = tok / 49;
    int wi = b_ & 63;  int b  = b_ >> 6;
    int th = t / 7, tw = t - th * 7;
    int hs = (wi >> 3) * 7 + th + 3; if (hs >= 56) hs -= 56;
    int vs = (wi & 7) * 7 + tw + 3;  if (vs >= 56) vs -= 56;
    const float2* row = (const float2*)(x + ((long)b * 3136 + hs * 56 + vs) * 384);
    float2 v[3]; float s = 0.f;
    #pragma unroll
    for (int i = 0; i < 3; ++i) { v[i] = row[lane + 64 * i]; s += v[i].x + v[i].y; }
    #pragma unroll
    for (int o = 32; o; o >>= 1) s += __shfl_xor(s, o);
    float mean = s * (1.f / 384.f);
    float q = 0.f;
    #pragma unroll
    for (int i = 0; i < 3; ++i) {
        float dx = v[i].x - mean, dy = v[i].y - mean; q += dx * dx + dy * dy;
    }
    #pragma unroll
    for (int o = 32; o; o >>= 1) q += __shfl_xor(q, o);
    float inv = rsqrtf(q * (1.f / 384.f) + 1e-5f);
    unsigned short* orow = xw + (long)tok * 384;
    #pragma unroll
    for (int i = 0; i < 3; ++i) {
        int c = i * 128 + lane * 2;
        unsigned int p = (unsigned int)f2bf((v[i].x - mean) * inv * g[c] + bb[c])
                       | ((unsigned int)f2bf((v[i].y - mean) * inv * g[c + 1] + bb[c + 1]) << 16);
        *(unsigned int*)(orow + c) = p;
    }
}

// ------- fused un-roll scatter + residual + LN2: out = x + gather(projout); h2 = LN2(out) -------
__global__ __launch_bounds__(256) void k_scln(const unsigned short* __restrict__ po,
                                              const float* __restrict__ x,
                                              const float* __restrict__ g,
                                              const float* __restrict__ bb,
                                              float* __restrict__ out,
                                              unsigned short* __restrict__ h2) {
    int wid = threadIdx.x >> 6, lane = threadIdx.x & 63;
    int tok = blockIdx.x * 4 + wid;                 // < 200704
    int b = tok / 3136, rem = tok - b * 3136;
    int hh = rem / 56, ww = rem - hh * 56;
    int u = (hh >= 3) ? hh - 3 : hh + 53;           // inverse roll(+3)
    int v = (ww >= 3) ? ww - 3 : ww + 53;
    int wr = u / 7, th = u - wr * 7;
    int wc = v / 7, tw = v - wc * 7;
    long src = ((long)((b << 6) + wr * 8 + wc) * 49 + th * 7 + tw) * 384;
    const unsigned int* prow = (const unsigned int*)(po + src);    // 2 bf16 / uint
    const float2* xrow = (const float2*)(x + (long)tok * 384);
    float2 o[3]; float s = 0.f;
    #pragma unroll
    for (int i = 0; i < 3; ++i) {
        unsigned int pb = prow[lane + 64 * i];
        float2 xv = xrow[lane + 64 * i];
        o[i].x = xv.x + bf2f((unsigned short)(pb & 0xffffu));
        o[i].y = xv.y + bf2f((unsigned short)(pb >> 16));
        s += o[i].x + o[i].y;
    }
    float2* orow = (float2*)(out + (long)tok * 384);
    #pragma unroll
    for (int i = 0; i < 3; ++i) orow[lane + 64 * i] = o[i];
    #pragma unroll
    for (int of = 32; of; of >>= 1) s += __shfl_xor(s, of);
    float mean = s * (1.f / 384.f);
    float q = 0.f;
    #pragma unroll
    for (int i = 0; i < 3; ++i) {
        float dx = o[i].x - mean, dy = o[i].y - mean; q += dx * dx + dy * dy;
    }
    #pragma unroll
    for (int of = 32; of; of >>= 1) q += __shfl_xor(q, of);
    float inv = rsqrtf(q * (1.f / 384.f) + 1e-5f);
    unsigned short* hrow = h2 + (long)tok * 384;
    #pragma unroll
    for (int i = 0; i < 3; ++i) {
        int c = i * 128 + lane * 2;
        unsigned int p = (unsigned int)f2bf((o[i].x - mean) * inv * g[c] + bb[c])
                       | ((unsigned int)f2bf((o[i].y - mean) * inv * g[c + 1] + bb[c + 1]) << 16);
        *(unsigned int*)(hrow + c) = p;
    }
}

// ---------------- MFMA windowed attention: 1 wave = 1 (window, head), 4 waves/block ----------------
__global__ __launch_bounds__(256) void k_attn(const unsigned short* __restrict__ qkv,
                                              const float* __restrict__ tbl,     // [4][12][64][64]
                                              unsigned short* __restrict__ aout, // [nwin*49,384]
                                              int win_base) {
    __shared__ unsigned short Plds[4][64][72];
    __shared__ unsigned short Vlds[4][32][72];
    int tid = threadIdx.x;
    int w = tid >> 6, lane = tid & 63;
    int wg = blockIdx.x * 4 + w;
    int lw = wg / 12;                  // local window
    int h  = wg - lw * 12;             // head
    int g  = lane >> 4, c = lane & 15;
    const unsigned short* base = qkv + (long)lw * 49 * 1152;

    int wi = (win_base + lw) & 63;
    int mt = ((wi >> 3) == 7 ? 1 : 0) | ((wi & 7) == 7 ? 2 : 0);
    const float* tb = tbl + ((long)(mt * 12 + h) << 12);

    // ---- stage V (permuted rows) into LDS; zero-fill padding rows 49..63 ----
    #pragma unroll
    for (int it = 0; it < 4; ++it) {
        int t = it * 64 + lane;        // t < 256
        int j = t >> 2, o = t & 3;
        int pj = 4 * (j & 15) + (j >> 4);     // phys slot
        if (j < 49) {
            u16x8 vv = *(const u16x8*)(base + (long)j * 1152 + 768 + h * 32 + o * 8);
            #pragma unroll
            for (int e = 0; e < 8; ++e) Vlds[w][o * 8 + e][pj] = vv[e];
        } else {
            #pragma unroll
            for (int e = 0; e < 8; ++e) Vlds[w][o * 8 + e][pj] = 0;
        }
    }

    // ---- Q and K fragments straight from global ----
    bf16x8 qa[4], kb[4];
    #pragma unroll
    for (int m = 0; m < 4; ++m) {
        int qr = 16 * m + c; if (qr > 48) qr = 48;
        qa[m] = *(const bf16x8*)(base + (long)qr * 1152 + h * 32 + 8 * g);
    }
    #pragma unroll
    for (int n = 0; n < 4; ++n) {
        int jr = 16 * n + c; if (jr > 48) jr = 48;
        kb[n] = *(const bf16x8*)(base + (long)jr * 1152 + 384 + h * 32 + 8 * g);
    }

    // ---- S = Q.K^T : 16 MFMA, single k-step ----
    f32x4 s[4][4];
    #pragma unroll
    for (int m = 0; m < 4; ++m)
        #pragma unroll
        for (int n = 0; n < 4; ++n) {
            s[m][n] = (f32x4){0.f, 0.f, 0.f, 0.f};
            s[m][n] = __builtin_amdgcn_mfma_f32_16x16x32_bf16(qa[m], kb[n], s[m][n], 0, 0, 0);
        }

    // ---- scale + bias/mask table; softmax rows in C/D layout ----
    #pragma unroll
    for (int m = 0; m < 4; ++m)
        #pragma unroll
        for (int n = 0; n < 4; ++n) {
            #pragma unroll
            for (int ii = 0; ii < 4; ++ii) {
                int i = 16 * m + 4 * g + ii, j = 16 * n + c;
                s[m][n][ii] = s[m][n][ii] * 0.17677669529663687f + tb[i * 64 + j];
            }
        }
    float inv[4][4];
    #pragma unroll
    for (int m = 0; m < 4; ++m) {
        #pragma unroll
        for (int ii = 0; ii < 4; ++ii) {
            float mx = fmaxf(fmaxf(s[m][0][ii], s[m][1][ii]), fmaxf(s[m][2][ii], s[m][3][ii]));
            #pragma unroll
            for (int o = 1; o < 16; o <<= 1) mx = fmaxf(mx, __shfl_xor(mx, o));
            float sm = 0.f;
            #pragma unroll
            for (int n = 0; n < 4; ++n) {
                float p = __expf(s[m][n][ii] - mx);
                s[m][n][ii] = p; sm += p;
            }
            #pragma unroll
            for (int o = 1; o < 16; o <<= 1) sm += __shfl_xor(sm, o);
            inv[m][ii] = 1.f / sm;
        }
    }

    // ---- P -> LDS: packed b64 writes at permuted cols phys(16n+c)=4c+n ----
    #pragma unroll
    for (int m = 0; m < 4; ++m)
        #pragma unroll
        for (int ii = 0; ii < 4; ++ii) {
            int r = 16 * m + 4 * g + ii;
            u16x4 pk;
            #pragma unroll
            for (int n = 0; n < 4; ++n) pk[n] = f2bf(s[m][n][ii]);
            *(u16x4*)&Plds[w][r][4 * c] = pk;
        }

    __syncthreads();

    // ---- O = P.V : 2 k-steps over 64 phys slots ----
    f32x4 o2[4][2];
    #pragma unroll
    for (int m = 0; m < 4; ++m)
        #pragma unroll
        for (int n = 0; n < 2; ++n) o2[m][n] = (f32x4){0.f, 0.f, 0.f, 0.f};
    #pragma unroll
    for (int ks = 0; ks < 2; ++ks) {
        bf16x8 pa[4], vb[2];
        #pragma unroll
        for (int m = 0; m < 4; ++m)
            pa[m] = *(const bf16x8*)&Plds[w][c + 16 * m][32 * ks + 8 * g];
        #pragma unroll
        for (int n = 0; n < 2; ++n)
            vb[n] = *(const bf16x8*)&Vlds[w][c + 16 * n][32 * ks + 8 * g];
        #pragma unroll
        for (int m = 0; m < 4; ++m)
            #pragma unroll
            for (int n = 0; n < 2; ++n)
                o2[m][n] = __builtin_amdgcn_mfma_f32_16x16x32_bf16(pa[m], vb[n], o2[m][n], 0, 0, 0);
    }

    // ---- store O rows < 49, scaled by 1/rowsum ----
    #pragma unroll
    for (int m = 0; m < 4; ++m)
        #pragma unroll
        for (int ii = 0; ii < 4; ++ii) {
            int i = 16 * m + 4 * g + ii;
            if (i < 49) {
                unsigned short* orow = aout + ((long)lw * 49 + i) * 384 + h * 32;
                #pragma unroll
                for (int n = 0; n < 2; ++n)
                    orow[c + 16 * n] = f2bf(o2[m][n][ii] * inv[m][ii]);
            }
        }
}

// ---------------- bf16 MFMA GEMM, 128x128 tile, BK=64, 4 waves, 2-phase dbuf ----------------
// Minimum 2-phase schedule (guide T3 recipe): STAGE(t+1) -> ds_read+MFMA(t) ->
// vmcnt(0) -> s_barrier. One barrier per K-step; loads hide under compute.
// LDS 64 KB -> 2 blocks/CU. Slot-XOR swizzle both-sides (m173). XCD swizzle (m204).
// EPI: 0 = bf16 out, 1 = bf16 out + exact GELU, 3 = f32 out + res (rows m_base+row)
template<int EPI>
__global__ __launch_bounds__(256) void k_gemm(
    const unsigned short* __restrict__ A,
    const unsigned short* __restrict__ Bt,
    const float* __restrict__ bias,
    unsigned short* outb, float* outf, const float* res,
    int M, int N, int K, int m_base)
{
    __shared__ unsigned short As[2][128][64];   // 32 KB
    __shared__ unsigned short Bs[2][128][64];   // 32 KB
    int nwg = gridDim.x * gridDim.y;
    int bid = blockIdx.y * gridDim.x + blockIdx.x;
    int qq = nwg >> 3, rr = nwg & 7;
    int xcd = bid & 7, idx = bid >> 3;
    int swz = (xcd < rr) ? (xcd * (qq + 1) + idx) : (rr * (qq + 1) + (xcd - rr) * qq + idx);
    int m0 = (swz / gridDim.x) << 7;
    int n0 = (swz % gridDim.x) << 7;

    int tid = threadIdx.x, wid = tid >> 6, lane = tid & 63;
    int wr = wid >> 1, wc = wid & 1;
    f32x4 acc[4][4];
    #pragma unroll
    for (int i = 0; i < 4; ++i)
        #pragma unroll
        for (int j = 0; j < 4; ++j)
            acc[i][j] = (f32x4){0.f, 0.f, 0.f, 0.f};

    // staging: wave stages 32 rows of A and 32 rows of B per K-tile (8 gload_lds).
    // LDS slot s of row r holds global k-slot s^(r&7)  (source pre-swizzle, m173)
    int lrow = lane >> 3;
    int lcol = (lane & 7) ^ lrow;
    const unsigned short* Ag = A  + (long)(m0 + wid * 32 + lrow) * K + lcol * 8;
    const unsigned short* Bg = Bt + (long)(n0 + wid * 32 + lrow) * K + lcol * 8;

    // hoisted LDS read offsets (element index within one [128][64] plane)
    int aofs[2][4], bofs[2][4];
    #pragma unroll
    for (int kk = 0; kk < 2; ++kk) {
        #pragma unroll
        for (int mi = 0; mi < 4; ++mi) {
            int r = wr * 64 + mi * 16 + (lane & 15);
            int slot = (kk * 4 + (lane >> 4)) ^ (r & 7);
            aofs[kk][mi] = r * 64 + slot * 8;
            r = wc * 64 + mi * 16 + (lane & 15);
            slot = (kk * 4 + (lane >> 4)) ^ (r & 7);
            bofs[kk][mi] = r * 64 + slot * 8;
        }
    }
    const unsigned short* Abase = &As[0][0][0];
    const unsigned short* Bbase = &Bs[0][0][0];

    int nt = K >> 6;
    auto stage = [&](int buf, int t) {
        int k0 = t << 6;
        #pragma unroll
        for (int c = 0; c < 4; ++c)
            __builtin_amdgcn_global_load_lds(
                (const __attribute__((address_space(1))) void*)(Ag + k0 + c * 8 * K),
                (__attribute__((address_space(3))) void*)(&As[buf][wid * 32 + c * 8][0]), 16, 0, 0);
        #pragma unroll
        for (int c = 0; c < 4; ++c)
            __builtin_amdgcn_global_load_lds(
                (const __attribute__((address_space(1))) void*)(Bg + k0 + c * 8 * K),
                (__attribute__((address_space(3))) void*)(&Bs[buf][wid * 32 + c * 8][0]), 16, 0, 0);
    };

    // prologue: tile 0 staged and published
    stage(0, 0);
    asm volatile("s_waitcnt vmcnt(0)" ::: "memory");
    __builtin_amdgcn_s_barrier();

    int buf = 0;
    for (int t = 0; t < nt; ++t) {
        if (t + 1 < nt) stage(buf ^ 1, t + 1);     // issue early: hides under MFMA below
        int bofs_base = buf * (128 * 64);
        #pragma unroll
        for (int kk = 0; kk < 2; ++kk) {
            bf16x8 af[4], bfr[4];
            #pragma unroll
            for (int mi = 0; mi < 4; ++mi)
                af[mi] = *reinterpret_cast<const bf16x8*>(Abase + bofs_base + aofs[kk][mi]);
            #pragma unroll
            for (int ni = 0; ni < 4; ++ni)
                bfr[ni] = *reinterpret_cast<const bf16x8*>(Bbase + bofs_base + bofs[kk][ni]);
            __builtin_amdgcn_s_setprio(1);
            #pragma unroll
            for (int mi = 0; mi < 4; ++mi)
                #pragma unroll
                for (int ni = 0; ni < 4; ++ni)
                    acc[mi][ni] = __builtin_amdgcn_mfma_f32_16x16x32_bf16(
                        af[mi], bfr[ni], acc[mi][ni], 0, 0, 0);
            __builtin_amdgcn_s_setprio(0);
        }
        if (t + 1 < nt) {
            asm volatile("s_waitcnt vmcnt(0)" ::: "memory");   // t+1's loads landed
            __builtin_amdgcn_s_barrier();                      // publish; reads of buf done
        }
        buf ^= 1;
    }

    #pragma unroll
    for (int mi = 0; mi < 4; ++mi) {
        #pragma unroll
        for (int ni = 0; ni < 4; ++ni) {
            int col = n0 + wc * 64 + ni * 16 + (lane & 15);
            float bv = bias[col];
            #pragma unroll
            for (int i = 0; i < 4; ++i) {
                int row = m0 + wr * 64 + mi * 16 + (lane >> 4) * 4 + i;
                float v = acc[mi][ni][i] + bv;
                if constexpr (EPI == 0) {
                    outb[(long)row * N + col] = f2bf(v);
                } else if constexpr (EPI == 1) {
                    outb[(long)row * N + col] = f2bf(0.5f * v * (1.f + erff(v * 0.70710678f)));
                } else {
                    long oidx = (long)(m_base + row) * 384 + col;
                    outf[oidx] = v + res[oidx];
                }
            }
        }
    }
}

extern "C" void kernel_launch(void* const* d_in, const int* in_sizes, int n_in,
                              void* d_out, int out_size, void* d_ws, size_t ws_size,
                              hipStream_t stream) {
    (void)in_sizes; (void)n_in; (void)out_size;
    const float* x     = (const float*)d_in[0];
    const float* n1g   = (const float*)d_in[1];
    const float* n1b   = (const float*)d_in[2];
    const float* qkvw  = (const float*)d_in[3];
    const float* qkvb  = (const float*)d_in[4];
    const float* rpb   = (const float*)d_in[5];
    const float* projw = (const float*)d_in[6];
    const float* projb = (const float*)d_in[7];
    const float* n2g   = (const float*)d_in[8];
    const float* n2b   = (const float*)d_in[9];
    const float* fc1w  = (const float*)d_in[10];
    const float* fc1b  = (const float*)d_in[11];
    const float* fc2w  = (const float*)d_in[12];
    const float* fc2b  = (const float*)d_in[13];
    float* out = (float*)d_out;

    const long Mtot = 200704;
    auto pad = [](size_t b) { return (b + 255) & ~(size_t)255; };
    size_t fixed = pad((size_t)1152 * 384 * 2) + pad((size_t)384 * 384 * 2)
                 + pad((size_t)1536 * 384 * 2) + pad((size_t)384 * 1536 * 2)
                 + pad((size_t)4 * 12 * 4096 * 4)
                 + pad((size_t)Mtot * 384 * 2)      // xw / h2
                 + pad((size_t)Mtot * 384 * 2);     // projout (full, chunk-independent)
    int nc = 1;
    while (nc < 8) {
        size_t rows = Mtot / nc;
        if (fixed + pad(rows * 1536 * 2) + pad(rows * 384 * 2) <= ws_size) break;
        nc <<= 1;
    }
    long rows = Mtot / nc;            // rows per chunk, multiple of 128 and 49
    int  mb   = (int)(rows >> 7);     // 128-row tiles per chunk
    int  wpc  = (int)(rows / 49);     // windows per chunk (multiple of 64)

    char* ws = (char*)d_ws;
    size_t off = 0;
    auto alloc = [&](size_t bytes) { char* p = ws + off; off += (bytes + 255) & ~(size_t)255; return p; };
    unsigned short* BtQ  = (unsigned short*)alloc((size_t)1152 * 384 * 2);
    unsigned short* BtP  = (unsigned short*)alloc((size_t)384 * 384 * 2);
    unsigned short* Bt1  = (unsigned short*)alloc((size_t)1536 * 384 * 2);
    unsigned short* Bt2  = (unsigned short*)alloc((size_t)384 * 1536 * 2);
    float*          tbl  = (float*)alloc((size_t)4 * 12 * 4096 * 4);
    unsigned short* xw   = (unsigned short*)alloc((size_t)Mtot * 384 * 2);   // xw, reused as h2
    unsigned short* pout = (unsigned short*)alloc((size_t)Mtot * 384 * 2);   // proj out (window order)
    unsigned short* bufB = (unsigned short*)alloc((size_t)rows * 1536 * 2);  // qkv / fc1 chunk
    unsigned short* attb = (unsigned short*)alloc((size_t)rows * 384 * 2);   // attn-out chunk

    k_transpose<<<dim3((1152 * 384 + 255) / 256), 256, 0, stream>>>(qkvw, BtQ, 384, 1152);
    k_transpose<<<dim3((384 * 384 + 255) / 256), 256, 0, stream>>>(projw, BtP, 384, 384);
    k_transpose<<<dim3((1536 * 384 + 255) / 256), 256, 0, stream>>>(fc1w, Bt1, 384, 1536);
    k_transpose<<<dim3((384 * 1536 + 255) / 256), 256, 0, stream>>>(fc2w, Bt2, 1536, 384);
    k_btab<<<dim3(768), 256, 0, stream>>>(rpb, tbl);

    k_ln1<<<dim3(50176), 256, 0, stream>>>(x, n1g, n1b, xw);

    // attention phase
    for (int c = 0; c < nc; ++c) {
        const unsigned short* Ax = xw + (size_t)c * rows * 384;
        k_gemm<0><<<dim3(9, mb), 256, 0, stream>>>(Ax, BtQ, qkvb, bufB, nullptr, nullptr,
                                                   (int)rows, 1152, 384, 0);
        k_attn<<<dim3(wpc * 3), 256, 0, stream>>>(bufB, tbl, attb, c * wpc);
        k_gemm<0><<<dim3(3, mb), 256, 0, stream>>>(attb, BtP, projb,
                                                   pout + (size_t)c * rows * 384,
                                                   nullptr, nullptr,
                                                   (int)rows, 384, 384, 0);
    }

    // fused un-roll scatter + residual + LN2 (writes out f32 and xw=h2 bf16)
    k_scln<<<dim3(50176), 256, 0, stream>>>(pout, x, n2g, n2b, out, xw);

    // MLP phase
    for (int c = 0; c < nc; ++c) {
        const unsigned short* Ah = xw + (size_t)c * rows * 384;
        k_gemm<1><<<dim3(12, mb), 256, 0, stream>>>(Ah, Bt1, fc1b, bufB, nullptr, nullptr,
                                                    (int)rows, 1536, 384, 0);
        k_gemm<3><<<dim3(3, mb), 256, 0, stream>>>(bufB, Bt2, fc2b, nullptr, out, out,
                                                   (int)rows, 384, 1536, (int)(c * rows));
    }
}

// Round 8
// 2024.821 us; speedup vs baseline: 1.0700x; 1.0275x over previous
//
#include <hip/hip_runtime.h>

// Swin block: LN1 -> shift+window -> qkv GEMM -> MFMA windowed attn -> proj GEMM (linear)
//          -> fused scatter+residual+LN2 -> fc1 GEMM(+GELU) -> fc2 GEMM(+residual)
// B=64, H=W=56, C=384, WS=7, SS=3, NH=12, hd=32, N=49, nW=64, B_=4096, M=200704
// R8: GEMM = 8-phase counted-vmcnt pipeline (T3+T4+T5), tile 128x384 (BK=64), 8 waves,
//     128 KB LDS (2buf x {1 A-half + 3 B-halves} x 16KB). One half-tile staged per phase;
//     vmcnt(2) at phases 4/8 (vmcnt(0) in final iter - staged-slot guard). All N here are
//     multiples of 384 so one geometry serves qkv/proj/fc1/fc2; A is read exactly once.

typedef __bf16 bf16x8 __attribute__((ext_vector_type(8)));
typedef float  f32x4  __attribute__((ext_vector_type(4)));
typedef unsigned short u16x8 __attribute__((ext_vector_type(8)));
typedef unsigned short u16x4 __attribute__((ext_vector_type(4)));

__device__ __forceinline__ unsigned short f2bf(float f) {
    unsigned int u = __builtin_bit_cast(unsigned int, f);
    u += 0x7fffu + ((u >> 16) & 1u);   // RNE
    return (unsigned short)(u >> 16);
}
__device__ __forceinline__ float bf2f(unsigned short h) {
    return __builtin_bit_cast(float, (unsigned int)h << 16);
}

// ---------------- weight transpose + cast: W[K,N] f32 -> Bt[N,K] bf16 ----------------
__global__ __launch_bounds__(256) void k_transpose(const float* __restrict__ W,
                                                   unsigned short* __restrict__ Bt,
                                                   int K, int N) {
    int idx = blockIdx.x * 256 + threadIdx.x;
    if (idx >= N * K) return;
    int n = idx / K, k = idx - n * K;
    Bt[idx] = f2bf(W[(long)k * N + n]);
}

// ---------------- bias+mask table: tbl[mt][h][i][j], 4*12*64*64 f32 ----------------
__global__ __launch_bounds__(256) void k_btab(const float* __restrict__ rpb,
                                              float* __restrict__ tbl) {
    int idx = blockIdx.x * 256 + threadIdx.x;
    if (idx >= 4 * 12 * 4096) return;
    int j = idx & 63, i = (idx >> 6) & 63;
    int slab = idx >> 12;            // mt*12 + h
    int h = slab % 12, mt = slab / 12;
    float v;
    if (j >= 49)      v = -30000.f;
    else if (i >= 49) v = 0.f;
    else {
        int ith = i / 7, itw = i - ith * 7;
        int jth = j / 7, jtw = j - jth * 7;
        v = rpb[((ith - jth + 6) * 13 + (itw - jtw + 6)) * 12 + h];
        bool m = ((mt & 1) && ((ith < 4) != (jth < 4))) ||
                 ((mt & 2) && ((itw < 4) != (jtw < 4)));
        if (m) v -= 100.f;
    }
    tbl[idx] = v;
}

// ---------------- LN1 + cyclic shift(-3,-3) + window partition ----------------
__global__ __launch_bounds__(256) void k_ln1(const float* __restrict__ x,
                                             const float* __restrict__ g,
                                             const float* __restrict__ bb,
                                             unsigned short* __restrict__ xw) {
    int wid = threadIdx.x >> 6, lane = threadIdx.x & 63;
    int tok = blockIdx.x * 4 + wid;                 // < 200704
    int t  = tok % 49; int b_ = tok / 49;
    int wi = b_ & 63;  int b  = b_ >> 6;
    int th = t / 7, tw = t - th * 7;
    int hs = (wi >> 3) * 7 + th + 3; if (hs >= 56) hs -= 56;
    int vs = (wi & 7) * 7 + tw + 3;  if (vs >= 56) vs -= 56;
    const float2* row = (const float2*)(x + ((long)b * 3136 + hs * 56 + vs) * 384);
    float2 v[3]; float s = 0.f;
    #pragma unroll
    for (int i = 0; i < 3; ++i) { v[i] = row[lane + 64 * i]; s += v[i].x + v[i].y; }
    #pragma unroll
    for (int o = 32; o; o >>= 1) s += __shfl_xor(s, o);
    float mean = s * (1.f / 384.f);
    float q = 0.f;
    #pragma unroll
    for (int i = 0; i < 3; ++i) {
        float dx = v[i].x - mean, dy = v[i].y - mean; q += dx * dx + dy * dy;
    }
    #pragma unroll
    for (int o = 32; o; o >>= 1) q += __shfl_xor(q, o);
    float inv = rsqrtf(q * (1.f / 384.f) + 1e-5f);
    unsigned short* orow = xw + (long)tok * 384;
    #pragma unroll
    for (int i = 0; i < 3; ++i) {
        int c = i * 128 + lane * 2;
        unsigned int p = (unsigned int)f2bf((v[i].x - mean) * inv * g[c] + bb[c])
                       | ((unsigned int)f2bf((v[i].y - mean) * inv * g[c + 1] + bb[c + 1]) << 16);
        *(unsigned int*)(orow + c) = p;
    }
}

// ------- fused un-roll scatter + residual + LN2: out = x + gather(projout); h2 = LN2(out) -------
__global__ __launch_bounds__(256) void k_scln(const unsigned short* __restrict__ po,
                                              const float* __restrict__ x,
                                              const float* __restrict__ g,
                                              const float* __restrict__ bb,
                                              float* __restrict__ out,
                                              unsigned short* __restrict__ h2) {
    int wid = threadIdx.x >> 6, lane = threadIdx.x & 63;
    int tok = blockIdx.x * 4 + wid;                 // < 200704
    int b = tok / 3136, rem = tok - b * 3136;
    int hh = rem / 56, ww = rem - hh * 56;
    int u = (hh >= 3) ? hh - 3 : hh + 53;           // inverse roll(+3)
    int v = (ww >= 3) ? ww - 3 : ww + 53;
    int wr = u / 7, th = u - wr * 7;
    int wc = v / 7, tw = v - wc * 7;
    long src = ((long)((b << 6) + wr * 8 + wc) * 49 + th * 7 + tw) * 384;
    const unsigned int* prow = (const unsigned int*)(po + src);    // 2 bf16 / uint
    const float2* xrow = (const float2*)(x + (long)tok * 384);
    float2 o[3]; float s = 0.f;
    #pragma unroll
    for (int i = 0; i < 3; ++i) {
        unsigned int pb = prow[lane + 64 * i];
        float2 xv = xrow[lane + 64 * i];
        o[i].x = xv.x + bf2f((unsigned short)(pb & 0xffffu));
        o[i].y = xv.y + bf2f((unsigned short)(pb >> 16));
        s += o[i].x + o[i].y;
    }
    float2* orow = (float2*)(out + (long)tok * 384);
    #pragma unroll
    for (int i = 0; i < 3; ++i) orow[lane + 64 * i] = o[i];
    #pragma unroll
    for (int of = 32; of; of >>= 1) s += __shfl_xor(s, of);
    float mean = s * (1.f / 384.f);
    float q = 0.f;
    #pragma unroll
    for (int i = 0; i < 3; ++i) {
        float dx = o[i].x - mean, dy = o[i].y - mean; q += dx * dx + dy * dy;
    }
    #pragma unroll
    for (int of = 32; of; of >>= 1) q += __shfl_xor(q, of);
    float inv = rsqrtf(q * (1.f / 384.f) + 1e-5f);
    unsigned short* hrow = h2 + (long)tok * 384;
    #pragma unroll
    for (int i = 0; i < 3; ++i) {
        int c = i * 128 + lane * 2;
        unsigned int p = (unsigned int)f2bf((o[i].x - mean) * inv * g[c] + bb[c])
                       | ((unsigned int)f2bf((o[i].y - mean) * inv * g[c + 1] + bb[c + 1]) << 16);
        *(unsigned int*)(hrow + c) = p;
    }
}

// ---------------- MFMA windowed attention: 1 wave = 1 (window, head), 4 waves/block ----------------
__global__ __launch_bounds__(256) void k_attn(const unsigned short* __restrict__ qkv,
                                              const float* __restrict__ tbl,     // [4][12][64][64]
                                              unsigned short* __restrict__ aout, // [nwin*49,384]
                                              int win_base) {
    __shared__ unsigned short Plds[4][64][72];
    __shared__ unsigned short Vlds[4][32][72];
    int tid = threadIdx.x;
    int w = tid >> 6, lane = tid & 63;
    int wg = blockIdx.x * 4 + w;
    int lw = wg / 12;                  // local window
    int h  = wg - lw * 12;             // head
    int g  = lane >> 4, c = lane & 15;
    const unsigned short* base = qkv + (long)lw * 49 * 1152;

    int wi = (win_base + lw) & 63;
    int mt = ((wi >> 3) == 7 ? 1 : 0) | ((wi & 7) == 7 ? 2 : 0);
    const float* tb = tbl + ((long)(mt * 12 + h) << 12);

    // ---- stage V (permuted rows) into LDS; zero-fill padding rows 49..63 ----
    #pragma unroll
    for (int it = 0; it < 4; ++it) {
        int t = it * 64 + lane;        // t < 256
        int j = t >> 2, o = t & 3;
        int pj = 4 * (j & 15) + (j >> 4);     // phys slot
        if (j < 49) {
            u16x8 vv = *(const u16x8*)(base + (long)j * 1152 + 768 + h * 32 + o * 8);
            #pragma unroll
            for (int e = 0; e < 8; ++e) Vlds[w][o * 8 + e][pj] = vv[e];
        } else {
            #pragma unroll
            for (int e = 0; e < 8; ++e) Vlds[w][o * 8 + e][pj] = 0;
        }
    }

    // ---- Q and K fragments straight from global ----
    bf16x8 qa[4], kb[4];
    #pragma unroll
    for (int m = 0; m < 4; ++m) {
        int qr = 16 * m + c; if (qr > 48) qr = 48;
        qa[m] = *(const bf16x8*)(base + (long)qr * 1152 + h * 32 + 8 * g);
    }
    #pragma unroll
    for (int n = 0; n < 4; ++n) {
        int jr = 16 * n + c; if (jr > 48) jr = 48;
        kb[n] = *(const bf16x8*)(base + (long)jr * 1152 + 384 + h * 32 + 8 * g);
    }

    // ---- S = Q.K^T : 16 MFMA, single k-step ----
    f32x4 s[4][4];
    #pragma unroll
    for (int m = 0; m < 4; ++m)
        #pragma unroll
        for (int n = 0; n < 4; ++n) {
            s[m][n] = (f32x4){0.f, 0.f, 0.f, 0.f};
            s[m][n] = __builtin_amdgcn_mfma_f32_16x16x32_bf16(qa[m], kb[n], s[m][n], 0, 0, 0);
        }

    // ---- scale + bias/mask table; softmax rows in C/D layout ----
    #pragma unroll
    for (int m = 0; m < 4; ++m)
        #pragma unroll
        for (int n = 0; n < 4; ++n) {
            #pragma unroll
            for (int ii = 0; ii < 4; ++ii) {
                int i = 16 * m + 4 * g + ii, j = 16 * n + c;
                s[m][n][ii] = s[m][n][ii] * 0.17677669529663687f + tb[i * 64 + j];
            }
        }
    float inv[4][4];
    #pragma unroll
    for (int m = 0; m < 4; ++m) {
        #pragma unroll
        for (int ii = 0; ii < 4; ++ii) {
            float mx = fmaxf(fmaxf(s[m][0][ii], s[m][1][ii]), fmaxf(s[m][2][ii], s[m][3][ii]));
            #pragma unroll
            for (int o = 1; o < 16; o <<= 1) mx = fmaxf(mx, __shfl_xor(mx, o));
            float sm = 0.f;
            #pragma unroll
            for (int n = 0; n < 4; ++n) {
                float p = __expf(s[m][n][ii] - mx);
                s[m][n][ii] = p; sm += p;
            }
            #pragma unroll
            for (int o = 1; o < 16; o <<= 1) sm += __shfl_xor(sm, o);
            inv[m][ii] = 1.f / sm;
        }
    }

    // ---- P -> LDS: packed b64 writes at permuted cols phys(16n+c)=4c+n ----
    #pragma unroll
    for (int m = 0; m < 4; ++m)
        #pragma unroll
        for (int ii = 0; ii < 4; ++ii) {
            int r = 16 * m + 4 * g + ii;
            u16x4 pk;
            #pragma unroll
            for (int n = 0; n < 4; ++n) pk[n] = f2bf(s[m][n][ii]);
            *(u16x4*)&Plds[w][r][4 * c] = pk;
        }

    __syncthreads();

    // ---- O = P.V : 2 k-steps over 64 phys slots ----
    f32x4 o2[4][2];
    #pragma unroll
    for (int m = 0; m < 4; ++m)
        #pragma unroll
        for (int n = 0; n < 2; ++n) o2[m][n] = (f32x4){0.f, 0.f, 0.f, 0.f};
    #pragma unroll
    for (int ks = 0; ks < 2; ++ks) {
        bf16x8 pa[4], vb[2];
        #pragma unroll
        for (int m = 0; m < 4; ++m)
            pa[m] = *(const bf16x8*)&Plds[w][c + 16 * m][32 * ks + 8 * g];
        #pragma unroll
        for (int n = 0; n < 2; ++n)
            vb[n] = *(const bf16x8*)&Vlds[w][c + 16 * n][32 * ks + 8 * g];
        #pragma unroll
        for (int m = 0; m < 4; ++m)
            #pragma unroll
            for (int n = 0; n < 2; ++n)
                o2[m][n] = __builtin_amdgcn_mfma_f32_16x16x32_bf16(pa[m], vb[n], o2[m][n], 0, 0, 0);
    }

    // ---- store O rows < 49, scaled by 1/rowsum ----
    #pragma unroll
    for (int m = 0; m < 4; ++m)
        #pragma unroll
        for (int ii = 0; ii < 4; ++ii) {
            int i = 16 * m + 4 * g + ii;
            if (i < 49) {
                unsigned short* orow = aout + ((long)lw * 49 + i) * 384 + h * 32;
                #pragma unroll
                for (int n = 0; n < 2; ++n)
                    orow[c + 16 * n] = f2bf(o2[m][n][ii] * inv[m][ii]);
            }
        }
}

// ---------------- 8-phase GEMM: tile 128x384, BK=64, 8 waves, counted vmcnt ----------------
// A[M,K] bf16 rm, Bt[N,K] bf16 rm. Half-tiles of 128 rows x 64 cols (16 KB): A has 1,
// B has 3 per K-tile. LDS = 2 buffers x 4 halves = 128 KB. One half staged per phase.
// Iter i computes tiles X=2i (buf0, P1-P4) and Y=2i+1 (buf1, P5-P8).
// Stage map: P1:b1(Y) P2:b2(Y) P3:a(Y) P4:b0(X+2) P5:b1(X+2) P6:b2(X+2) P7:a(X+2) P8:b0(Y+2)
// Write-safety: each slot restaged strictly after its last reader phase's trailing barrier.
// Visibility: vmcnt(2)@P4 publishes {b1,b2,a}(Y); vmcnt(2)@P8 publishes all X+2 halves.
// Final iter: stages guarded off -> vmcnt(0) (else the 2 left in flight would be a(Y)).
// Slot-XOR swizzle (source pre-swizzle, m173): LDS chunk s of local row r holds global
// chunk s^(r&7); reads use slot = (kk*4+gg)^(r&7). Verified conflict-free since R5.
// EPI: 0 = bf16 out, 1 = bf16 out + exact GELU, 3 = f32 out + res (rows m_base+row)
#define GEMM_FENCE asm volatile("" ::: "memory")
#define GEMM_BAR  { GEMM_FENCE; __builtin_amdgcn_s_barrier(); GEMM_FENCE; }

template<int EPI>
__global__ __launch_bounds__(512, 2) void k8(
    const unsigned short* __restrict__ A,
    const unsigned short* __restrict__ Bt,
    const float* __restrict__ bias,
    unsigned short* outb, float* outf, const float* res,
    int Ntot, int K, int m_base)
{
    __shared__ unsigned short Asl[2][8192];      // [buf][128*64]           32 KB
    __shared__ unsigned short Bsl[2][3][8192];   // [buf][half][128*64]     96 KB

    int nwg = gridDim.x * gridDim.y;
    int bid = blockIdx.y * gridDim.x + blockIdx.x;
    int qq = nwg >> 3, rr = nwg & 7;
    int xcd = bid & 7, idx = bid >> 3;
    int swz = (xcd < rr) ? (xcd * (qq + 1) + idx) : (rr * (qq + 1) + (xcd - rr) * qq + idx);
    int m0 = (swz / gridDim.x) << 7;         // 128-row tiles
    int n0 = (swz % gridDim.x) * 384;        // 384-col tiles

    int tid = threadIdx.x, wid = tid >> 6, lane = tid & 63;
    int wr = wid >> 2, wc = wid & 3;         // 2M x 4N waves; per-wave 64x96
    int gg = lane >> 4, cc = lane & 15;

    f32x4 acc[4][6];
    #pragma unroll
    for (int i = 0; i < 4; ++i)
        #pragma unroll
        for (int j = 0; j < 6; ++j)
            acc[i][j] = (f32x4){0.f, 0.f, 0.f, 0.f};

    // staging addresses: half = 1024 chunks of 8 bf16; thread covers u = c*512+tid, c=0,1
    // local row r = u>>3, slot s = u&7, global chunk = s^(r&7)  (pre-swizzled source)
    int u0 = tid, u1 = 512 + tid;
    int r0 = u0 >> 3, s0 = (u0 & 7) ^ (r0 & 7);
    int r1 = u1 >> 3, s1 = (u1 & 7) ^ (r1 & 7);
    long aoff0 = (long)(m0 + r0) * K + s0 * 8;
    long aoff1 = (long)(m0 + r1) * K + s1 * 8;
    long boff0 = (long)(n0 + r0) * K + s0 * 8;
    long boff1 = (long)(n0 + r1) * K + s1 * 8;
    int dstA0 = wid * 64 * 8, dstA1 = (512 + wid * 64) * 8;   // element offsets (wave-uniform)

#define GLL16(srcp, dst) __builtin_amdgcn_global_load_lds( \
        (const __attribute__((address_space(1))) void*)(srcp), \
        (__attribute__((address_space(3))) void*)(dst), 16, 0, 0)

    auto STAGE_A = [&](int buf, int t) {
        GLL16(A + aoff0 + (long)t * 64, &Asl[buf][dstA0]);
        GLL16(A + aoff1 + (long)t * 64, &Asl[buf][dstA1]);
    };
    auto STAGE_B = [&](int buf, int half, int t) {
        long ho = (long)half * 128 * K;
        GLL16(Bt + boff0 + ho + (long)t * 64, &Bsl[buf][half][dstA0]);
        GLL16(Bt + boff1 + ho + (long)t * 64, &Bsl[buf][half][dstA1]);
    };

    bf16x8 bfr[6], af[2];
    auto rdA = [&](int buf, int kk, int Mh) {
        #pragma unroll
        for (int mi = 0; mi < 2; ++mi) {
            int lr = wr * 64 + Mh * 32 + mi * 16 + cc;
            int sl = (kk * 4 + gg) ^ (lr & 7);
            af[mi] = *(const bf16x8*)&Asl[buf][lr * 64 + sl * 8];
        }
    };
    auto rdB = [&](int buf, int kk) {
        #pragma unroll
        for (int ni = 0; ni < 6; ++ni) {
            int col = wc * 96 + ni * 16 + cc;
            int bh = col >> 7, lr = col & 127;
            int sl = (kk * 4 + gg) ^ (lr & 7);
            bfr[ni] = *(const bf16x8*)&Bsl[buf][bh][lr * 64 + sl * 8];
        }
    };
    auto MM = [&](int Mh) {
        __builtin_amdgcn_s_setprio(1);
        #pragma unroll
        for (int mi = 0; mi < 2; ++mi)
            #pragma unroll
            for (int ni = 0; ni < 6; ++ni)
                acc[Mh * 2 + mi][ni] = __builtin_amdgcn_mfma_f32_16x16x32_bf16(
                    af[mi], bfr[ni], acc[Mh * 2 + mi][ni], 0, 0, 0);
        __builtin_amdgcn_s_setprio(0);
    };

    int nt = K >> 6, niter = nt >> 1;

    // prologue: tile 0 fully + b0 of tile 1; publish
    STAGE_A(0, 0);
    STAGE_B(0, 0, 0); STAGE_B(0, 1, 0); STAGE_B(0, 2, 0);
    STAGE_B(1, 0, 1);
    asm volatile("s_waitcnt vmcnt(0)" ::: "memory");
    GEMM_BAR;

    for (int i = 0; i < niter; ++i) {
        int X = 2 * i, Y = X + 1;
        bool g = (X + 2 < nt);
        // P1
        rdB(0, 0); rdA(0, 0, 0);
        STAGE_B(1, 1, Y);
        GEMM_BAR; MM(0); GEMM_BAR;
        // P2
        rdA(0, 0, 1);
        STAGE_B(1, 2, Y);
        GEMM_BAR; MM(1); GEMM_BAR;
        // P3
        rdB(0, 1); rdA(0, 1, 0);
        STAGE_A(1, Y);
        GEMM_BAR; MM(0); GEMM_BAR;
        // P4  (publish {b1,b2,a}(Y))
        rdA(0, 1, 1);
        if (g) {
            STAGE_B(0, 0, X + 2);
            asm volatile("s_waitcnt vmcnt(2)" ::: "memory");
        } else {
            asm volatile("s_waitcnt vmcnt(0)" ::: "memory");
        }
        GEMM_BAR; MM(1); GEMM_BAR;
        // P5
        rdB(1, 0); rdA(1, 0, 0);
        if (g) STAGE_B(0, 1, X + 2);
        GEMM_BAR; MM(0); GEMM_BAR;
        // P6
        rdA(1, 0, 1);
        if (g) STAGE_B(0, 2, X + 2);
        GEMM_BAR; MM(1); GEMM_BAR;
        // P7
        rdB(1, 1); rdA(1, 1, 0);
        if (g) STAGE_A(0, X + 2);
        GEMM_BAR; MM(0); GEMM_BAR;
        // P8  (publish all X+2 halves)
        rdA(1, 1, 1);
        if (g) {
            STAGE_B(1, 0, Y + 2);
            asm volatile("s_waitcnt vmcnt(2)" ::: "memory");
        } else {
            asm volatile("s_waitcnt vmcnt(0)" ::: "memory");
        }
        GEMM_BAR; MM(1); GEMM_BAR;
    }

    #pragma unroll
    for (int mi2 = 0; mi2 < 4; ++mi2) {
        #pragma unroll
        for (int ni = 0; ni < 6; ++ni) {
            int col = n0 + wc * 96 + ni * 16 + cc;
            float bv = bias[col];
            #pragma unroll
            for (int i = 0; i < 4; ++i) {
                int row = m0 + wr * 64 + mi2 * 16 + gg * 4 + i;
                float v = acc[mi2][ni][i] + bv;
                if constexpr (EPI == 0) {
                    outb[(long)row * Ntot + col] = f2bf(v);
                } else if constexpr (EPI == 1) {
                    outb[(long)row * Ntot + col] = f2bf(0.5f * v * (1.f + erff(v * 0.70710678f)));
                } else {
                    long oidx = (long)(m_base + row) * 384 + col;
                    outf[oidx] = v + res[oidx];
                }
            }
        }
    }
}

extern "C" void kernel_launch(void* const* d_in, const int* in_sizes, int n_in,
                              void* d_out, int out_size, void* d_ws, size_t ws_size,
                              hipStream_t stream) {
    (void)in_sizes; (void)n_in; (void)out_size;
    const float* x     = (const float*)d_in[0];
    const float* n1g   = (const float*)d_in[1];
    const float* n1b   = (const float*)d_in[2];
    const float* qkvw  = (const float*)d_in[3];
    const float* qkvb  = (const float*)d_in[4];
    const float* rpb   = (const float*)d_in[5];
    const float* projw = (const float*)d_in[6];
    const float* projb = (const float*)d_in[7];
    const float* n2g   = (const float*)d_in[8];
    const float* n2b   = (const float*)d_in[9];
    const float* fc1w  = (const float*)d_in[10];
    const float* fc1b  = (const float*)d_in[11];
    const float* fc2w  = (const float*)d_in[12];
    const float* fc2b  = (const float*)d_in[13];
    float* out = (float*)d_out;

    const long Mtot = 200704;
    auto pad = [](size_t b) { return (b + 255) & ~(size_t)255; };
    size_t fixed = pad((size_t)1152 * 384 * 2) + pad((size_t)384 * 384 * 2)
                 + pad((size_t)1536 * 384 * 2) + pad((size_t)384 * 1536 * 2)
                 + pad((size_t)4 * 12 * 4096 * 4)
                 + pad((size_t)Mtot * 384 * 2)      // xw / h2
                 + pad((size_t)Mtot * 384 * 2);     // projout (full, chunk-independent)
    int nc = 1;
    while (nc < 8) {
        size_t rows = Mtot / nc;
        if (fixed + pad(rows * 1536 * 2) + pad(rows * 384 * 2) <= ws_size) break;
        nc <<= 1;
    }
    long rows = Mtot / nc;            // rows per chunk, multiple of 128 and 49
    int  mb   = (int)(rows >> 7);     // 128-row tiles per chunk
    int  wpc  = (int)(rows / 49);     // windows per chunk (multiple of 64)

    char* ws = (char*)d_ws;
    size_t off = 0;
    auto alloc = [&](size_t bytes) { char* p = ws + off; off += (bytes + 255) & ~(size_t)255; return p; };
    unsigned short* BtQ  = (unsigned short*)alloc((size_t)1152 * 384 * 2);
    unsigned short* BtP  = (unsigned short*)alloc((size_t)384 * 384 * 2);
    unsigned short* Bt1  = (unsigned short*)alloc((size_t)1536 * 384 * 2);
    unsigned short* Bt2  = (unsigned short*)alloc((size_t)384 * 1536 * 2);
    float*          tbl  = (float*)alloc((size_t)4 * 12 * 4096 * 4);
    unsigned short* xw   = (unsigned short*)alloc((size_t)Mtot * 384 * 2);   // xw, reused as h2
    unsigned short* pout = (unsigned short*)alloc((size_t)Mtot * 384 * 2);   // proj out (window order)
    unsigned short* bufB = (unsigned short*)alloc((size_t)rows * 1536 * 2);  // qkv / fc1 chunk
    unsigned short* attb = (unsigned short*)alloc((size_t)rows * 384 * 2);   // attn-out chunk

    k_transpose<<<dim3((1152 * 384 + 255) / 256), 256, 0, stream>>>(qkvw, BtQ, 384, 1152);
    k_transpose<<<dim3((384 * 384 + 255) / 256), 256, 0, stream>>>(projw, BtP, 384, 384);
    k_transpose<<<dim3((1536 * 384 + 255) / 256), 256, 0, stream>>>(fc1w, Bt1, 384, 1536);
    k_transpose<<<dim3((384 * 1536 + 255) / 256), 256, 0, stream>>>(fc2w, Bt2, 1536, 384);
    k_btab<<<dim3(768), 256, 0, stream>>>(rpb, tbl);

    k_ln1<<<dim3(50176), 256, 0, stream>>>(x, n1g, n1b, xw);

    // attention phase
    for (int c = 0; c < nc; ++c) {
        const unsigned short* Ax = xw + (size_t)c * rows * 384;
        k8<0><<<dim3(3, mb), 512, 0, stream>>>(Ax, BtQ, qkvb, bufB, nullptr, nullptr,
                                               1152, 384, 0);
        k_attn<<<dim3(wpc * 3), 256, 0, stream>>>(bufB, tbl, attb, c * wpc);
        k8<0><<<dim3(1, mb), 512, 0, stream>>>(attb, BtP, projb,
                                               pout + (size_t)c * rows * 384,
                                               nullptr, nullptr,
                                               384, 384, 0);
    }

    // fused un-roll scatter + residual + LN2 (writes out f32 and xw=h2 bf16)
    k_scln<<<dim3(50176), 256, 0, stream>>>(pout, x, n2g, n2b, out, xw);

    // MLP phase
    for (int c = 0; c < nc; ++c) {
        const unsigned short* Ah = xw + (size_t)c * rows * 384;
        k8<1><<<dim3(4, mb), 512, 0, stream>>>(Ah, Bt1, fc1b, bufB, nullptr, nullptr,
                                               1536, 384, 0);
        k8<3><<<dim3(1, mb), 512, 0, stream>>>(bufB, Bt2, fc2b, nullptr, out, out,
                                               384, 1536, (int)(c * rows));
    }
}